// Round 8
// baseline (108.149 us; speedup 1.0000x reference)
//
#include <hip/hip_runtime.h>

// LTPE: y(p) = x(p) - sum_j w_j * x(p + off_j), zero-padded borders,
// then instance-norm over HxW per image: (y - mean) * rsqrt(var + 4e-5).
// (The reference's out = 0.5*y + 0.5; instance norm is affine-invariant,
//  with eps folding 1e-5 -> 4e-5.)
//
// Two plain kernels (fusion via coop/atomic barriers measured 130-170us
// worse; shuffle-halos measured +11us worse than scalar halo loads).
// This round: round-6 loader (vector load + 2 edge scalars) + 2-deep row
// prefetch pipeline + NBLK=64 (2048 blocks -> 8 blocks/CU, 100% occupancy,
// enforced via __launch_bounds__(256,8)). Norm pass issues its initial row
// loads BEFORE the stats reduce so the reduce hides under load latency.

#define HH 1024
#define WW 1024
#define NIMG 32
#define NBLK 64                  // blocks per image
#define RPB (HH / NBLK)          // 16 rows per block
#define TPB 256                  // = WW/4 float4 columns per row

typedef float vfloat4 __attribute__((ext_vector_type(4)));

// weights: j=0..7 -> 2^j/255, offsets (dy,dx):
// j0 (0,-1), j1 (1,-1), j2 (1,0), j3 (1,1), j4 (0,1), j5 (-1,1), j6 (-1,0), j7 (-1,-1)
__device__ __forceinline__ void compute_y(const float* up, const float* mid,
                                          const float* dn, float* y) {
    const float w0 = 1.f / 255.f,  w1 = 2.f / 255.f,  w2 = 4.f / 255.f,
                w3 = 8.f / 255.f,  w4 = 16.f / 255.f, w5 = 32.f / 255.f,
                w6 = 64.f / 255.f, w7 = 128.f / 255.f;
#pragma unroll
    for (int k = 0; k < 4; ++k) {
        float s = w0 * mid[k] + w4 * mid[k + 2]
                + w1 * dn[k]  + w2 * dn[k + 1] + w3 * dn[k + 2]
                + w7 * up[k]  + w6 * up[k + 1] + w5 * up[k + 2];
        y[k] = mid[k + 1] - s;
    }
}

// buf[0]=left halo, buf[1..4]=vfloat4, buf[5]=right halo; zeros out of range
__device__ __forceinline__ void load_row_g(const float* __restrict__ base,
                                           int r, int c, float* buf) {
    if (r < 0 || r >= HH) {
#pragma unroll
        for (int k = 0; k < 6; ++k) buf[k] = 0.f;
        return;
    }
    const float* row = base + (size_t)r * WW;
    const vfloat4 v = reinterpret_cast<const vfloat4*>(row)[c];
    buf[0] = (c > 0) ? row[4 * c - 1] : 0.f;
    buf[1] = v.x; buf[2] = v.y; buf[3] = v.z; buf[4] = v.w;
    buf[5] = (c < TPB - 1) ? row[4 * c + 4] : 0.f;
}

template <bool NORM>
__global__ __launch_bounds__(TPB, 8) void ltpe_pass(const float* __restrict__ x,
                                                    float* __restrict__ partials,
                                                    float* __restrict__ out) {
    const int img = blockIdx.x / NBLK;
    const int blk = blockIdx.x % NBLK;
    const int c = threadIdx.x;
    const float* base = x + (size_t)img * HH * WW;
    const int r0 = blk * RPB;

    // rolling 4-row register pipeline: iter i uses buf[i&3]=row r-1,
    // buf[(i+1)&3]=row r, buf[(i+2)&3]=row r+1; prefetches row r+3 into
    // buf[i&3] (2 iterations ahead of its use as dn). Loads issued FIRST
    // so the NORM stats reduce below overlaps their latency.
    float buf[4][6];
    load_row_g(base, r0 - 1, c, buf[0]);
    load_row_g(base, r0,     c, buf[1]);
    load_row_g(base, r0 + 1, c, buf[2]);
    load_row_g(base, r0 + 2, c, buf[3]);

    float mean = 0.f, scale = 1.f;
    if (NORM) {
        // redundant per-block final reduce of this image's 64 partials
        __shared__ float sh_stats[2];
        if (threadIdx.x < 64) {
            const int lane = threadIdx.x;
            double S = (double)partials[img * NBLK + lane];
            double SS = (double)partials[NIMG * NBLK + img * NBLK + lane];
#pragma unroll
            for (int off = 32; off > 0; off >>= 1) {
                S += __shfl_down(S, off);
                SS += __shfl_down(SS, off);
            }
            if (lane == 0) {
                const double N = (double)HH * (double)WW;
                const double m = S / N;
                const double var = SS / N - m * m;
                sh_stats[0] = (float)m;
                sh_stats[1] = (float)(1.0 / sqrt(var + 4e-5)); // 4*eps folds 0.5
            }
        }
        __syncthreads();
        mean = sh_stats[0];
        scale = sh_stats[1];
    }

    float s = 0.f, ss = 0.f;
    float* obase = out + (size_t)img * HH * WW;

#pragma unroll
    for (int i = 0; i < RPB; ++i) {
        const int r = r0 + i;
        float y[4];
        compute_y(buf[i & 3], buf[(i + 1) & 3], buf[(i + 2) & 3], y);
        if (NORM) {
            vfloat4 o;
            o.x = (y[0] - mean) * scale;
            o.y = (y[1] - mean) * scale;
            o.z = (y[2] - mean) * scale;
            o.w = (y[3] - mean) * scale;
            // nt: don't let the 128 MB output stream evict x from L3
            __builtin_nontemporal_store(
                o, reinterpret_cast<vfloat4*>(obase + (size_t)r * WW) + c);
        } else {
#pragma unroll
            for (int k = 0; k < 4; ++k) { s += y[k]; ss = fmaf(y[k], y[k], ss); }
        }
        if (i + 2 < RPB)  // row r+3 serves as dn in iter i+2
            load_row_g(base, r + 3, c, buf[i & 3]);
    }

    if (!NORM) {
        // block reduction: wave64 shuffle, then LDS across 4 waves
#pragma unroll
        for (int off = 32; off > 0; off >>= 1) {
            s += __shfl_down(s, off);
            ss += __shfl_down(ss, off);
        }
        __shared__ float sh[8];
        const int wave = threadIdx.x >> 6;
        const int lane = threadIdx.x & 63;
        if (lane == 0) { sh[wave] = s; sh[4 + wave] = ss; }
        __syncthreads();
        if (threadIdx.x == 0) {
            partials[img * NBLK + blk] = sh[0] + sh[1] + sh[2] + sh[3];
            partials[NIMG * NBLK + img * NBLK + blk] = sh[4] + sh[5] + sh[6] + sh[7];
        }
    }
}

extern "C" void kernel_launch(void* const* d_in, const int* in_sizes, int n_in,
                              void* d_out, int out_size, void* d_ws, size_t ws_size,
                              hipStream_t stream) {
    const float* x = (const float*)d_in[0];
    float* out = (float*)d_out;
    float* partials = (float*)d_ws; // [NIMG*NBLK sums][NIMG*NBLK sumsqs]

    ltpe_pass<false><<<NIMG * NBLK, TPB, 0, stream>>>(x, partials, out);
    ltpe_pass<true><<<NIMG * NBLK, TPB, 0, stream>>>(x, partials, out);
}

// Round 9
// 96.164 us; speedup vs baseline: 1.1246x; 1.1246x over previous
//
#include <hip/hip_runtime.h>

// LTPE: y(p) = x(p) - sum_j w_j * x(p + off_j), zero-padded borders,
// then instance-norm over HxW per image: (y - mean) * rsqrt(var + 4e-5).
// (The reference's out = 0.5*y + 0.5; instance norm is affine-invariant,
//  with eps folding 1e-5 -> 4e-5.)
//
// Round 9 structure: pass 1 computes y once, stores it as bf16 (RNE) into
// ws (64 MB, regular stores -> L3-resident) + per-block stats partials.
// Pass 2 is pure elementwise: reduce partials, read bf16 y (L3 hits),
// write f32 out with nt stores. Eliminates the second stencil pass and
// 64 MB of HBM read vs the recompute design.
// (Round 8 lesson: __launch_bounds__(,8) caused VGPR=32 cap -> scratch
// spills -> 111us/pass. No min-wave bounds here.)

#define HH 1024
#define WW 1024
#define HW (HH * WW)
#define NIMG 32
#define NBLK1 32                 // pass-1 blocks per image
#define RPB1 (HH / NBLK1)        // 32 rows per block
#define NBLK2 64                 // pass-2 blocks per image
#define EPB2 (HW / NBLK2)        // 16384 elements per pass-2 block
#define TPB 256

typedef float vfloat4 __attribute__((ext_vector_type(4)));
typedef unsigned short vushort4 __attribute__((ext_vector_type(4)));
typedef unsigned short vushort8 __attribute__((ext_vector_type(8)));

// weights: j=0..7 -> 2^j/255, offsets (dy,dx):
// j0 (0,-1), j1 (1,-1), j2 (1,0), j3 (1,1), j4 (0,1), j5 (-1,1), j6 (-1,0), j7 (-1,-1)
__device__ __forceinline__ void compute_y(const float* up, const float* mid,
                                          const float* dn, float* y) {
    const float w0 = 1.f / 255.f,  w1 = 2.f / 255.f,  w2 = 4.f / 255.f,
                w3 = 8.f / 255.f,  w4 = 16.f / 255.f, w5 = 32.f / 255.f,
                w6 = 64.f / 255.f, w7 = 128.f / 255.f;
#pragma unroll
    for (int k = 0; k < 4; ++k) {
        float s = w0 * mid[k] + w4 * mid[k + 2]
                + w1 * dn[k]  + w2 * dn[k + 1] + w3 * dn[k + 2]
                + w7 * up[k]  + w6 * up[k + 1] + w5 * up[k + 2];
        y[k] = mid[k + 1] - s;
    }
}

// buf[0]=left halo, buf[1..4]=vfloat4, buf[5]=right halo; zeros out of range
__device__ __forceinline__ void load_row_g(const float* __restrict__ base,
                                           int r, int c, float* buf) {
    if (r < 0 || r >= HH) {
#pragma unroll
        for (int k = 0; k < 6; ++k) buf[k] = 0.f;
        return;
    }
    const float* row = base + (size_t)r * WW;
    const vfloat4 v = reinterpret_cast<const vfloat4*>(row)[c];
    buf[0] = (c > 0) ? row[4 * c - 1] : 0.f;
    buf[1] = v.x; buf[2] = v.y; buf[3] = v.z; buf[4] = v.w;
    buf[5] = (c < TPB - 1) ? row[4 * c + 4] : 0.f;
}

__device__ __forceinline__ unsigned short f32_to_bf16_rne(float f) {
    unsigned int u = __float_as_uint(f);
    u += 0x7fffu + ((u >> 16) & 1u);  // round-to-nearest-even (no NaN inputs)
    return (unsigned short)(u >> 16);
}

// ---------------- pass 1: stencil -> bf16 y + stats partials ----------------
__global__ __launch_bounds__(TPB) void ltpe_stats(const float* __restrict__ x,
                                                  float* __restrict__ partials,
                                                  unsigned short* __restrict__ yb) {
    const int img = blockIdx.x / NBLK1;
    const int blk = blockIdx.x % NBLK1;
    const int c = threadIdx.x;
    const float* base = x + (size_t)img * HW;
    unsigned short* ybase = yb + (size_t)img * HW;
    const int r0 = blk * RPB1;

    // rolling 4-row register pipeline (2-deep prefetch), fully unrolled
    float buf[4][6];
    load_row_g(base, r0 - 1, c, buf[0]);
    load_row_g(base, r0,     c, buf[1]);
    load_row_g(base, r0 + 1, c, buf[2]);
    load_row_g(base, r0 + 2, c, buf[3]);

    float s = 0.f, ss = 0.f;
#pragma unroll
    for (int i = 0; i < RPB1; ++i) {
        const int r = r0 + i;
        float y[4];
        compute_y(buf[i & 3], buf[(i + 1) & 3], buf[(i + 2) & 3], y);
#pragma unroll
        for (int k = 0; k < 4; ++k) { s += y[k]; ss = fmaf(y[k], y[k], ss); }
        vushort4 h;
        h.x = f32_to_bf16_rne(y[0]);
        h.y = f32_to_bf16_rne(y[1]);
        h.z = f32_to_bf16_rne(y[2]);
        h.w = f32_to_bf16_rne(y[3]);
        reinterpret_cast<vushort4*>(ybase + (size_t)r * WW)[c] = h;
        if (i + 2 < RPB1)  // row r+3 serves as dn in iter i+2
            load_row_g(base, r + 3, c, buf[i & 3]);
    }

    // block reduction: wave64 shuffle, then LDS across 4 waves
#pragma unroll
    for (int off = 32; off > 0; off >>= 1) {
        s += __shfl_down(s, off);
        ss += __shfl_down(ss, off);
    }
    __shared__ float sh[8];
    const int wave = threadIdx.x >> 6;
    const int lane = threadIdx.x & 63;
    if (lane == 0) { sh[wave] = s; sh[4 + wave] = ss; }
    __syncthreads();
    if (threadIdx.x == 0) {
        partials[img * NBLK1 + blk] = sh[0] + sh[1] + sh[2] + sh[3];
        partials[NIMG * NBLK1 + img * NBLK1 + blk] = sh[4] + sh[5] + sh[6] + sh[7];
    }
}

// ------------- pass 2: reduce + elementwise normalize (no stencil) -------------
__global__ __launch_bounds__(TPB) void ltpe_norm(const unsigned short* __restrict__ yb,
                                                 const float* __restrict__ partials,
                                                 float* __restrict__ out) {
    const int img = blockIdx.x / NBLK2;
    const int blk = blockIdx.x % NBLK2;

    // redundant per-block final reduce of this image's 32 partials (one wave)
    __shared__ float sh_stats[2];
    if (threadIdx.x < 64) {
        const int lane = threadIdx.x;
        double S = 0.0, SS = 0.0;
        if (lane < NBLK1) {
            S = (double)partials[img * NBLK1 + lane];
            SS = (double)partials[NIMG * NBLK1 + img * NBLK1 + lane];
        }
#pragma unroll
        for (int off = 32; off > 0; off >>= 1) {
            S += __shfl_down(S, off);
            SS += __shfl_down(SS, off);
        }
        if (lane == 0) {
            const double N = (double)HW;
            const double m = S / N;
            const double var = SS / N - m * m;
            sh_stats[0] = (float)m;
            sh_stats[1] = (float)(1.0 / sqrt(var + 4e-5)); // 4*eps folds the 0.5
        }
    }
    __syncthreads();
    const float mean = sh_stats[0];
    const float scale = sh_stats[1];

    const size_t base = (size_t)img * HW + (size_t)blk * EPB2;
    const unsigned short* yp = yb + base;
    float* op = out + base;

#pragma unroll
    for (int i = 0; i < EPB2 / (TPB * 8); ++i) {  // 8 iterations
        const int idx = i * TPB * 8 + threadIdx.x * 8;
        const vushort8 h = *reinterpret_cast<const vushort8*>(yp + idx);
        vfloat4 o0, o1;
        o0.x = fmaf(__uint_as_float((unsigned int)h[0] << 16) - mean, scale, 0.f);
        o0.y = (__uint_as_float((unsigned int)h[1] << 16) - mean) * scale;
        o0.z = (__uint_as_float((unsigned int)h[2] << 16) - mean) * scale;
        o0.w = (__uint_as_float((unsigned int)h[3] << 16) - mean) * scale;
        o1.x = (__uint_as_float((unsigned int)h[4] << 16) - mean) * scale;
        o1.y = (__uint_as_float((unsigned int)h[5] << 16) - mean) * scale;
        o1.z = (__uint_as_float((unsigned int)h[6] << 16) - mean) * scale;
        o1.w = (__uint_as_float((unsigned int)h[7] << 16) - mean) * scale;
        o0.x = (__uint_as_float((unsigned int)h[0] << 16) - mean) * scale;
        // nt: streaming output must not evict the bf16 y buffer from L3
        __builtin_nontemporal_store(o0, reinterpret_cast<vfloat4*>(op + idx));
        __builtin_nontemporal_store(o1, reinterpret_cast<vfloat4*>(op + idx + 4));
    }
}

extern "C" void kernel_launch(void* const* d_in, const int* in_sizes, int n_in,
                              void* d_out, int out_size, void* d_ws, size_t ws_size,
                              hipStream_t stream) {
    const float* x = (const float*)d_in[0];
    float* out = (float*)d_out;
    // ws layout: [2*NIMG*NBLK1 partials floats][pad to 64KB][NIMG*HW bf16 y]
    float* partials = (float*)d_ws;
    unsigned short* yb = (unsigned short*)((char*)d_ws + 65536);

    ltpe_stats<<<NIMG * NBLK1, TPB, 0, stream>>>(x, partials, yb);
    ltpe_norm<<<NIMG * NBLK2, TPB, 0, stream>>>(yb, partials, out);
}

// Round 10
// 92.480 us; speedup vs baseline: 1.1694x; 1.0398x over previous
//
#include <hip/hip_runtime.h>

// LTPE: y(p) = x(p) - sum_j w_j * x(p + off_j), zero-padded borders,
// then instance-norm over HxW per image: (y - mean) * rsqrt(var + 4e-5).
// (The reference's out = 0.5*y + 0.5; instance norm is affine-invariant,
//  with eps folding 1e-5 -> 4e-5.)
//
// Structure (round 9/10): pass 1 computes y once, stores bf16 y into ws
// (L3-resident) + per-block stats partials. Pass 2 is pure elementwise
// (measured ~14-16us): reduce partials, read bf16 y (L3 hits), nt-write
// f32 out. Round-10 fix: stats pass was latency-bound at 1024 blocks
// (occupancy 23%, 80us) -> NBLK1=64 (2048 blocks, 8/CU). No min-wave
// launch_bounds (round 8: VGPR cap -> spills -> 111us).

#define HH 1024
#define WW 1024
#define HW (HH * WW)
#define NIMG 32
#define NBLK1 64                 // pass-1 blocks per image
#define RPB1 (HH / NBLK1)        // 16 rows per block
#define NBLK2 64                 // pass-2 blocks per image
#define EPB2 (HW / NBLK2)        // 16384 elements per pass-2 block
#define TPB 256

typedef float vfloat4 __attribute__((ext_vector_type(4)));
typedef unsigned short vushort4 __attribute__((ext_vector_type(4)));
typedef unsigned short vushort8 __attribute__((ext_vector_type(8)));

// weights: j=0..7 -> 2^j/255, offsets (dy,dx):
// j0 (0,-1), j1 (1,-1), j2 (1,0), j3 (1,1), j4 (0,1), j5 (-1,1), j6 (-1,0), j7 (-1,-1)
__device__ __forceinline__ void compute_y(const float* up, const float* mid,
                                          const float* dn, float* y) {
    const float w0 = 1.f / 255.f,  w1 = 2.f / 255.f,  w2 = 4.f / 255.f,
                w3 = 8.f / 255.f,  w4 = 16.f / 255.f, w5 = 32.f / 255.f,
                w6 = 64.f / 255.f, w7 = 128.f / 255.f;
#pragma unroll
    for (int k = 0; k < 4; ++k) {
        float s = w0 * mid[k] + w4 * mid[k + 2]
                + w1 * dn[k]  + w2 * dn[k + 1] + w3 * dn[k + 2]
                + w7 * up[k]  + w6 * up[k + 1] + w5 * up[k + 2];
        y[k] = mid[k + 1] - s;
    }
}

// buf[0]=left halo, buf[1..4]=vfloat4, buf[5]=right halo; zeros out of range
__device__ __forceinline__ void load_row_g(const float* __restrict__ base,
                                           int r, int c, float* buf) {
    if (r < 0 || r >= HH) {
#pragma unroll
        for (int k = 0; k < 6; ++k) buf[k] = 0.f;
        return;
    }
    const float* row = base + (size_t)r * WW;
    const vfloat4 v = reinterpret_cast<const vfloat4*>(row)[c];
    buf[0] = (c > 0) ? row[4 * c - 1] : 0.f;
    buf[1] = v.x; buf[2] = v.y; buf[3] = v.z; buf[4] = v.w;
    buf[5] = (c < TPB - 1) ? row[4 * c + 4] : 0.f;
}

__device__ __forceinline__ unsigned short f32_to_bf16_rne(float f) {
    unsigned int u = __float_as_uint(f);
    u += 0x7fffu + ((u >> 16) & 1u);  // round-to-nearest-even (no NaN inputs)
    return (unsigned short)(u >> 16);
}

// ---------------- pass 1: stencil -> bf16 y + stats partials ----------------
__global__ __launch_bounds__(TPB) void ltpe_stats(const float* __restrict__ x,
                                                  float* __restrict__ partials,
                                                  unsigned short* __restrict__ yb) {
    const int img = blockIdx.x / NBLK1;
    const int blk = blockIdx.x % NBLK1;
    const int c = threadIdx.x;
    const float* base = x + (size_t)img * HW;
    unsigned short* ybase = yb + (size_t)img * HW;
    const int r0 = blk * RPB1;

    // rolling 4-row register pipeline (2-deep prefetch), fully unrolled
    float buf[4][6];
    load_row_g(base, r0 - 1, c, buf[0]);
    load_row_g(base, r0,     c, buf[1]);
    load_row_g(base, r0 + 1, c, buf[2]);
    load_row_g(base, r0 + 2, c, buf[3]);

    float s = 0.f, ss = 0.f;
#pragma unroll
    for (int i = 0; i < RPB1; ++i) {
        const int r = r0 + i;
        float y[4];
        compute_y(buf[i & 3], buf[(i + 1) & 3], buf[(i + 2) & 3], y);
#pragma unroll
        for (int k = 0; k < 4; ++k) { s += y[k]; ss = fmaf(y[k], y[k], ss); }
        vushort4 h;
        h.x = f32_to_bf16_rne(y[0]);
        h.y = f32_to_bf16_rne(y[1]);
        h.z = f32_to_bf16_rne(y[2]);
        h.w = f32_to_bf16_rne(y[3]);
        reinterpret_cast<vushort4*>(ybase + (size_t)r * WW)[c] = h;
        if (i + 2 < RPB1)  // row r+3 serves as dn in iter i+2
            load_row_g(base, r + 3, c, buf[i & 3]);
    }

    // block reduction: wave64 shuffle, then LDS across 4 waves
#pragma unroll
    for (int off = 32; off > 0; off >>= 1) {
        s += __shfl_down(s, off);
        ss += __shfl_down(ss, off);
    }
    __shared__ float sh[8];
    const int wave = threadIdx.x >> 6;
    const int lane = threadIdx.x & 63;
    if (lane == 0) { sh[wave] = s; sh[4 + wave] = ss; }
    __syncthreads();
    if (threadIdx.x == 0) {
        partials[img * NBLK1 + blk] = sh[0] + sh[1] + sh[2] + sh[3];
        partials[NIMG * NBLK1 + img * NBLK1 + blk] = sh[4] + sh[5] + sh[6] + sh[7];
    }
}

// ------------- pass 2: reduce + elementwise normalize (no stencil) -------------
__global__ __launch_bounds__(TPB) void ltpe_norm(const unsigned short* __restrict__ yb,
                                                 const float* __restrict__ partials,
                                                 float* __restrict__ out) {
    const int img = blockIdx.x / NBLK2;
    const int blk = blockIdx.x % NBLK2;

    // redundant per-block final reduce of this image's 64 partials (one wave)
    __shared__ float sh_stats[2];
    if (threadIdx.x < 64) {
        const int lane = threadIdx.x;
        double S = (double)partials[img * NBLK1 + lane];
        double SS = (double)partials[NIMG * NBLK1 + img * NBLK1 + lane];
#pragma unroll
        for (int off = 32; off > 0; off >>= 1) {
            S += __shfl_down(S, off);
            SS += __shfl_down(SS, off);
        }
        if (lane == 0) {
            const double N = (double)HW;
            const double m = S / N;
            const double var = SS / N - m * m;
            sh_stats[0] = (float)m;
            sh_stats[1] = (float)(1.0 / sqrt(var + 4e-5)); // 4*eps folds the 0.5
        }
    }
    __syncthreads();
    const float mean = sh_stats[0];
    const float scale = sh_stats[1];

    const size_t base = (size_t)img * HW + (size_t)blk * EPB2;
    const unsigned short* yp = yb + base;
    float* op = out + base;

#pragma unroll
    for (int i = 0; i < EPB2 / (TPB * 8); ++i) {  // 8 iterations
        const int idx = i * TPB * 8 + threadIdx.x * 8;
        const vushort8 h = *reinterpret_cast<const vushort8*>(yp + idx);
        vfloat4 o0, o1;
        o0.x = (__uint_as_float((unsigned int)h[0] << 16) - mean) * scale;
        o0.y = (__uint_as_float((unsigned int)h[1] << 16) - mean) * scale;
        o0.z = (__uint_as_float((unsigned int)h[2] << 16) - mean) * scale;
        o0.w = (__uint_as_float((unsigned int)h[3] << 16) - mean) * scale;
        o1.x = (__uint_as_float((unsigned int)h[4] << 16) - mean) * scale;
        o1.y = (__uint_as_float((unsigned int)h[5] << 16) - mean) * scale;
        o1.z = (__uint_as_float((unsigned int)h[6] << 16) - mean) * scale;
        o1.w = (__uint_as_float((unsigned int)h[7] << 16) - mean) * scale;
        // nt: streaming output must not evict the bf16 y buffer from L3
        __builtin_nontemporal_store(o0, reinterpret_cast<vfloat4*>(op + idx));
        __builtin_nontemporal_store(o1, reinterpret_cast<vfloat4*>(op + idx + 4));
    }
}

extern "C" void kernel_launch(void* const* d_in, const int* in_sizes, int n_in,
                              void* d_out, int out_size, void* d_ws, size_t ws_size,
                              hipStream_t stream) {
    const float* x = (const float*)d_in[0];
    float* out = (float*)d_out;
    // ws layout: [2*NIMG*NBLK1 partials floats][pad to 64KB][NIMG*HW bf16 y]
    float* partials = (float*)d_ws;
    unsigned short* yb = (unsigned short*)((char*)d_ws + 65536);

    ltpe_stats<<<NIMG * NBLK1, TPB, 0, stream>>>(x, partials, yb);
    ltpe_norm<<<NIMG * NBLK2, TPB, 0, stream>>>(yb, partials, out);
}

// Round 11
// 69.688 us; speedup vs baseline: 1.5519x; 1.3271x over previous
//
#include <hip/hip_runtime.h>

// LTPE: y(p) = x(p) - sum_j w_j * x(p + off_j), zero-padded borders,
// then instance-norm over HxW per image: (y - mean) * rsqrt(var + 4e-5).
// (The reference's out = 0.5*y + 0.5; instance norm is affine-invariant,
//  with eps folding 1e-5 -> 4e-5.)
//
// Recompute skeleton (round-6, session best 70.9us). Round-11 change:
// pass 1 (pure read + reduce, NO stores -> no vmcnt store hazard) goes to
// NBLK1=64 (2048 blocks) to double resident waves; pass 2 (stencil +
// nt store) stays at NBLK2=32 which measured best. bf16-y-cache structure
// abandoned: same total traffic, store-interleaved stencil measured 2.6x
// slower than its traffic floor (rounds 9/10).

#define HH 1024
#define WW 1024
#define HW (HH * WW)
#define NIMG 32
#define NBLK1 64                 // pass-1 blocks per image (pure read)
#define RPB1 (HH / NBLK1)        // 16 rows per block
#define NBLK2 32                 // pass-2 blocks per image (read + nt store)
#define RPB2 (HH / NBLK2)        // 32 rows per block
#define TPB 256                  // = WW/4 float4 columns per row

typedef float vfloat4 __attribute__((ext_vector_type(4)));

// weights: j=0..7 -> 2^j/255, offsets (dy,dx):
// j0 (0,-1), j1 (1,-1), j2 (1,0), j3 (1,1), j4 (0,1), j5 (-1,1), j6 (-1,0), j7 (-1,-1)
__device__ __forceinline__ void compute_y(const float* up, const float* mid,
                                          const float* dn, float* y) {
    const float w0 = 1.f / 255.f,  w1 = 2.f / 255.f,  w2 = 4.f / 255.f,
                w3 = 8.f / 255.f,  w4 = 16.f / 255.f, w5 = 32.f / 255.f,
                w6 = 64.f / 255.f, w7 = 128.f / 255.f;
#pragma unroll
    for (int k = 0; k < 4; ++k) {
        float s = w0 * mid[k] + w4 * mid[k + 2]
                + w1 * dn[k]  + w2 * dn[k + 1] + w3 * dn[k + 2]
                + w7 * up[k]  + w6 * up[k + 1] + w5 * up[k + 2];
        y[k] = mid[k + 1] - s;
    }
}

// buf[0]=left halo, buf[1..4]=vfloat4, buf[5]=right halo; zeros out of range
__device__ __forceinline__ void load_row_g(const float* __restrict__ base,
                                           int r, int c, float* buf) {
    if (r < 0 || r >= HH) {
#pragma unroll
        for (int k = 0; k < 6; ++k) buf[k] = 0.f;
        return;
    }
    const float* row = base + (size_t)r * WW;
    const vfloat4 v = reinterpret_cast<const vfloat4*>(row)[c];
    buf[0] = (c > 0) ? row[4 * c - 1] : 0.f;
    buf[1] = v.x; buf[2] = v.y; buf[3] = v.z; buf[4] = v.w;
    buf[5] = (c < TPB - 1) ? row[4 * c + 4] : 0.f;
}

// ---------------- pass 1: pure-read stencil -> stats partials ----------------
__global__ __launch_bounds__(TPB) void ltpe_stats(const float* __restrict__ x,
                                                  float* __restrict__ partials) {
    const int img = blockIdx.x / NBLK1;
    const int blk = blockIdx.x % NBLK1;
    const int c = threadIdx.x;
    const float* base = x + (size_t)img * HW;
    const int r0 = blk * RPB1;

    // rolling 4-row register pipeline (2-deep prefetch), fully unrolled
    float buf[4][6];
    load_row_g(base, r0 - 1, c, buf[0]);
    load_row_g(base, r0,     c, buf[1]);
    load_row_g(base, r0 + 1, c, buf[2]);
    load_row_g(base, r0 + 2, c, buf[3]);

    float s = 0.f, ss = 0.f;
#pragma unroll
    for (int i = 0; i < RPB1; ++i) {
        const int r = r0 + i;
        float y[4];
        compute_y(buf[i & 3], buf[(i + 1) & 3], buf[(i + 2) & 3], y);
#pragma unroll
        for (int k = 0; k < 4; ++k) { s += y[k]; ss = fmaf(y[k], y[k], ss); }
        if (i + 2 < RPB1)  // row r+3 serves as dn in iter i+2
            load_row_g(base, r + 3, c, buf[i & 3]);
    }

    // block reduction: wave64 shuffle, then LDS across 4 waves
#pragma unroll
    for (int off = 32; off > 0; off >>= 1) {
        s += __shfl_down(s, off);
        ss += __shfl_down(ss, off);
    }
    __shared__ float sh[8];
    const int wave = threadIdx.x >> 6;
    const int lane = threadIdx.x & 63;
    if (lane == 0) { sh[wave] = s; sh[4 + wave] = ss; }
    __syncthreads();
    if (threadIdx.x == 0) {
        partials[img * NBLK1 + blk] = sh[0] + sh[1] + sh[2] + sh[3];
        partials[NIMG * NBLK1 + img * NBLK1 + blk] = sh[4] + sh[5] + sh[6] + sh[7];
    }
}

// ------------- pass 2: reduce head + stencil recompute + nt store -------------
__global__ __launch_bounds__(TPB) void ltpe_norm(const float* __restrict__ x,
                                                 const float* __restrict__ partials,
                                                 float* __restrict__ out) {
    const int img = blockIdx.x / NBLK2;
    const int blk = blockIdx.x % NBLK2;
    const int c = threadIdx.x;
    const float* base = x + (size_t)img * HW;
    const int r0 = blk * RPB2;

    // issue initial pipeline loads first so the reduce hides under them
    float buf[4][6];
    load_row_g(base, r0 - 1, c, buf[0]);
    load_row_g(base, r0,     c, buf[1]);
    load_row_g(base, r0 + 1, c, buf[2]);
    load_row_g(base, r0 + 2, c, buf[3]);

    // redundant per-block final reduce of this image's 64 partials (one wave)
    __shared__ float sh_stats[2];
    if (threadIdx.x < 64) {
        const int lane = threadIdx.x;
        double S = (double)partials[img * NBLK1 + lane];
        double SS = (double)partials[NIMG * NBLK1 + img * NBLK1 + lane];
#pragma unroll
        for (int off = 32; off > 0; off >>= 1) {
            S += __shfl_down(S, off);
            SS += __shfl_down(SS, off);
        }
        if (lane == 0) {
            const double N = (double)HW;
            const double m = S / N;
            const double var = SS / N - m * m;
            sh_stats[0] = (float)m;
            sh_stats[1] = (float)(1.0 / sqrt(var + 4e-5)); // 4*eps folds the 0.5
        }
    }
    __syncthreads();
    const float mean = sh_stats[0];
    const float scale = sh_stats[1];

    float* obase = out + (size_t)img * HW;

#pragma unroll
    for (int i = 0; i < RPB2; ++i) {
        const int r = r0 + i;
        float y[4];
        compute_y(buf[i & 3], buf[(i + 1) & 3], buf[(i + 2) & 3], y);
        vfloat4 o;
        o.x = (y[0] - mean) * scale;
        o.y = (y[1] - mean) * scale;
        o.z = (y[2] - mean) * scale;
        o.w = (y[3] - mean) * scale;
        // nt streaming store for the 128 MB output
        __builtin_nontemporal_store(
            o, reinterpret_cast<vfloat4*>(obase + (size_t)r * WW) + c);
        if (i + 2 < RPB2)  // row r+3 serves as dn in iter i+2
            load_row_g(base, r + 3, c, buf[i & 3]);
    }
}

extern "C" void kernel_launch(void* const* d_in, const int* in_sizes, int n_in,
                              void* d_out, int out_size, void* d_ws, size_t ws_size,
                              hipStream_t stream) {
    const float* x = (const float*)d_in[0];
    float* out = (float*)d_out;
    float* partials = (float*)d_ws; // [NIMG*NBLK1 sums][NIMG*NBLK1 sumsqs]

    ltpe_stats<<<NIMG * NBLK1, TPB, 0, stream>>>(x, partials);
    ltpe_norm<<<NIMG * NBLK2, TPB, 0, stream>>>(x, partials, out);
}